// Round 1
// 122.529 us; speedup vs baseline: 1.1835x; 1.1835x over previous
//
#include <hip/hip_runtime.h>
#include <stdint.h>

#define BS 8
#define LQ 256
#define HH 192
#define WW 192
#define HW (HH*WW)          /* 36864 pixels per plane */
#define KK 16
#define SITES 9216          /* float4 sites per plane */
#define SLICE_SITES 2304    /* 4 slices */
#define NSLICE 4
#define CAP 128             /* per (query,slice) candidate capacity */
#define PAD_FILT 4e-5f      /* filter safety: fma-vs-exact error ~1e-6 */

typedef unsigned long long u64;

// ---------- helpers ----------

__device__ __forceinline__ uint32_t fkey(float f) {
    uint32_t u = __float_as_uint(f);
    uint32_t mask = (uint32_t)((int32_t)u >> 31) | 0x80000000u;
    return u ^ mask;
}
__device__ __forceinline__ float inv_fkey(uint32_t v) {
    uint32_t u = (v & 0x80000000u) ? (v ^ 0x80000000u) : ~v;
    return __uint_as_float(u);
}

__device__ __forceinline__ u64 umin64(u64 a, u64 b) { return a < b ? a : b; }

__device__ __forceinline__ u64 wave_min_u64(u64 v) {
    #pragma unroll
    for (int off = 32; off >= 1; off >>= 1) {
        uint32_t lo = (uint32_t)v, hi = (uint32_t)(v >> 32);
        lo = __shfl_xor(lo, off, 64);
        hi = __shfl_xor(hi, off, 64);
        u64 o = ((u64)hi << 32) | lo;
        v = umin64(v, o);
    }
    return v;
}

// sorted ascending insertion, 16 deep (fallback path only)
__device__ __forceinline__ void insert64(u64 (&kept)[KK], u64 key) {
    #pragma unroll
    for (int j = KK - 1; j >= 1; --j) {
        u64 a = kept[j - 1];
        u64 mn = umin64(kept[j], key);
        kept[j] = (key < a) ? a : mn;
    }
    kept[0] = umin64(kept[0], key);
}

// sorted ascending insertion, 4 deep (u32 keys)
__device__ __forceinline__ void insert4(uint32_t (&k)[4], uint32_t key) {
    #pragma unroll
    for (int j = 3; j >= 1; --j) {
        uint32_t a = k[j - 1];
        uint32_t mn = min(k[j], key);
        k[j] = (key < a) ? a : mn;
    }
    k[0] = min(k[0], key);
}

// binary search: smallest key 'hi' with wave-count(kept <= hi) >= 16 (sound upper bound
// at every iteration since the invariant count(<=hi) >= 16 is maintained)
__device__ __forceinline__ uint32_t refine_tau4(const uint32_t (&kk)[4], int iters) {
    uint32_t lo = 0x00800000u, hi = 0xFF7FFFFFu;
    #pragma unroll 1
    for (int t = 0; t < iters; ++t) {
        uint32_t mid = lo + ((hi - lo) >> 1);
        int c = 0;
        #pragma unroll
        for (int j = 0; j < 4; ++j) c += (kk[j] <= mid) ? 1 : 0;
        #pragma unroll
        for (int off = 32; off >= 1; off >>= 1) c += __shfl_xor(c, off, 64);
        if (c >= KK) hi = mid; else lo = mid + 1;
    }
    return hi;
}

// exact (reference-rounded) similarity pieces — bit-identical to validated kernel
__device__ __forceinline__ float exact_rsq(float a, float b, float c) {
    return __fadd_rn(__fadd_rn(__fmul_rn(a, a), __fmul_rn(b, b)), __fmul_rn(c, c));
}
__device__ __forceinline__ float exact_sim(float c0, float c1, float c2, float rsq, float4 pq) {
    float cr = __fadd_rn(__fadd_rn(__fmul_rn(c0, pq.x), __fmul_rn(c1, pq.y)), __fmul_rn(c2, pq.z));
    return __fadd_rn(__fsub_rn(rsq, __fmul_rn(2.0f, cr)), pq.w);
}

// loss-term tracking for one extracted (rank-ordered) candidate; strict < keeps
// the first (lowest-rank) minimum == jnp.argmin tie-break
#define LOSS_STEP(gmv)                                                   \
{                                                                        \
    uint32_t idxv = (uint32_t)(gmv);                                     \
    float tx = (float)(idxv % WW) / 192.0f;                              \
    float ty = (float)(idxv / WW) / 192.0f;                              \
    float ddx = __fsub_rn(px1, tx);                                      \
    float ddy = __fsub_rn(py1, ty);                                      \
    float dd = __fadd_rn(__fmul_rn(ddx, ddx), __fmul_rn(ddy, ddy));      \
    if (dd < dmin) { dmin = dd; btx = tx; bty = ty; }                    \
}

// ---------- kernel 0: pooled + sound filter threshold per query ----------
// 1 wave per query; samples 2048 sites (8192 px); h = (16th-largest d over
// sample) - PAD_FILT, where d = dot3(ref,pooled) - 0.5*rsq in fma form,
// identical to the scan kernel's formula.
__global__ __launch_bounds__(256) void tau_kernel(const float* __restrict__ pred,
                                                  const float* __restrict__ ref,
                                                  float4* __restrict__ paramsA,
                                                  float4* __restrict__ paramsB) {
    int lane = threadIdx.x & 63;
    int wid  = threadIdx.x >> 6;
    int b = blockIdx.x & 7;            // XCD swizzle: image b -> XCD b
    int g = blockIdx.x >> 3;           // 0..63
    int l = g * 4 + wid;               // 0..255
    int bl = b * 256 + l;

    // pooled (all lanes redundantly; uniform) — verbatim reference rounding
    int i = l * BS + b;                // scrambled flat grid row
    int b2 = i >> 8, l2 = i & 255;
    const float* pr = pred + ((b2 * 256 + l2) * 8);
    float x = pr[0], y = pr[1];
    float fx = rintf(__fsub_rn(__fmul_rn(x, 192.0f), 0.5f));
    float fy = rintf(__fsub_rn(__fmul_rn(y, 192.0f), 0.5f));
    int ix = (int)fx, iy = (int)fy;
    int inb = (ix >= 0 && ix < WW && iy >= 0 && iy < HH) ? 1 : 0;
    int ixc = min(max(ix, 0), WW - 1);
    int iyc = min(max(iy, 0), HH - 1);
    float m = (float)inb;
    const float* img = ref + b * 3 * HW + iyc * WW + ixc;
    float p0 = __fmul_rn(img[0], m);
    float p1 = __fmul_rn(img[HW], m);
    float p2 = __fmul_rn(img[2 * HW], m);
    float psq = __fadd_rn(__fadd_rn(__fmul_rn(p0, p0), __fmul_rn(p1, p1)), __fmul_rn(p2, p2));

    const float4* p0g = (const float4*)(ref + (size_t)b * 3 * HW);

    uint32_t kept[4] = {~0u, ~0u, ~0u, ~0u};   // fkey(-d): ascending = largest d first
    #pragma unroll 2
    for (int it = 0; it < 32; ++it) {
        int j = it * 64 + lane;                // 0..2047
        int site = (j * 9) >> 1;               // spread over [0, 9216)
        float4 a0 = p0g[site], a1 = p0g[site + SITES], a2 = p0g[site + 2 * SITES];
        #define SAMP(comp)                                                              \
        {                                                                               \
            float rsf = fmaf(a2.comp, a2.comp, fmaf(a1.comp, a1.comp,                   \
                              a0.comp * a0.comp));                                      \
            float nr  = -0.5f * rsf;                                                    \
            float d   = fmaf(a2.comp, p2, fmaf(a1.comp, p1, fmaf(a0.comp, p0, nr)));    \
            uint32_t k = fkey(-d);                                                      \
            if (k < kept[3]) insert4(kept, k);                                          \
        }
        SAMP(x) SAMP(y) SAMP(z) SAMP(w)
        #undef SAMP
    }

    uint32_t tk = refine_tau4(kept, 24);
    float h = -inv_fkey(tk) - PAD_FILT;    // sound: h <= d_fma of every true top-16 px

    if (lane == 0) {
        paramsA[bl] = make_float4(p0, p1, p2, h);
        paramsB[bl] = make_float4(p0, p1, p2, psq);
    }
}

// ---------- kernel 1: shared scan — block = (image, 8 queries, 1/4 image) ----------
__global__ __launch_bounds__(256) void scan_kernel(const float* __restrict__ ref,
                                                   const float4* __restrict__ paramsA,
                                                   uint32_t* __restrict__ qcand,
                                                   uint32_t* __restrict__ qcnt) {
    __shared__ uint32_t qd[8][CAP];   // 4 KB
    __shared__ uint32_t cnt[8];

    int tid  = threadIdx.x;
    int lane = tid & 63;
    int wid  = tid >> 6;
    int b  = blockIdx.x & 7;          // XCD swizzle
    int r  = blockIdx.x >> 3;         // 0..127
    int qg = r & 31;                  // query group (8 queries)
    int s  = r >> 5;                  // slice 0..3
    int qbase = b * 256 + qg * 8;

    if (tid < 8) cnt[tid] = 0;

    // per-query filter params: wave-uniform -> scalar loads / SGPRs
    float px[8], py[8], pz[8], hh[8];
    #pragma unroll
    for (int q = 0; q < 8; ++q) {
        float4 pa = paramsA[qbase + q];
        px[q] = pa.x; py[q] = pa.y; pz[q] = pa.z; hh[q] = pa.w;
    }
    __syncthreads();

    const float4* p0g = (const float4*)(ref + (size_t)b * 3 * HW);
    int site = s * SLICE_SITES + tid;
    float4 n0 = p0g[site], n1 = p0g[site + SITES], n2 = p0g[site + 2 * SITES];

    #pragma unroll 1
    for (int it = 0; it < 9; ++it) {           // 9 * 256 sites = one slice
        float4 a0 = n0, a1 = n1, a2 = n2;
        int sn = (it < 8) ? (site + 256) : site;   // clamp last prefetch (stay in-bounds)
        n0 = p0g[sn]; n1 = p0g[sn + SITES]; n2 = p0g[sn + 2 * SITES];
        int base = site * 4;

        // shared across all 8 queries: -0.5*||ref||^2 per component
        float nrx = -0.5f * fmaf(a2.x, a2.x, fmaf(a1.x, a1.x, a0.x * a0.x));
        float nry = -0.5f * fmaf(a2.y, a2.y, fmaf(a1.y, a1.y, a0.y * a0.y));
        float nrz = -0.5f * fmaf(a2.z, a2.z, fmaf(a1.z, a1.z, a0.z * a0.z));
        float nrw = -0.5f * fmaf(a2.w, a2.w, fmaf(a1.w, a1.w, a0.w * a0.w));

        #pragma unroll
        for (int q = 0; q < 8; ++q) {
            float dx = fmaf(a2.x, pz[q], fmaf(a1.x, py[q], fmaf(a0.x, px[q], nrx)));
            float dy = fmaf(a2.y, pz[q], fmaf(a1.y, py[q], fmaf(a0.y, px[q], nry)));
            float dz = fmaf(a2.z, pz[q], fmaf(a1.z, py[q], fmaf(a0.z, px[q], nrz)));
            float dw = fmaf(a2.w, pz[q], fmaf(a1.w, py[q], fmaf(a0.w, px[q], nrw)));
            bool g0 = dx >= hh[q];
            bool g1 = dy >= hh[q];
            bool g2 = dz >= hh[q];
            bool g3 = dw >= hh[q];
            if (__ballot(g0 | g1 | g2 | g3)) {
                #define PUSHI(gc, ei)                                          \
                if (gc) {                                                      \
                    uint32_t slot = atomicAdd(&cnt[q], 1u);                    \
                    if (slot < CAP) qd[q][slot] = (uint32_t)(base + ei);       \
                }
                PUSHI(g0, 0) PUSHI(g1, 1) PUSHI(g2, 2) PUSHI(g3, 3)
                #undef PUSHI
            }
        }
        site += 256;
    }
    __syncthreads();

    // write queues to global (raw count preserved as overflow signal)
    for (int q = wid; q < 8; q += 4) {
        uint32_t c  = cnt[q];
        uint32_t cc = c < CAP ? c : CAP;
        uint32_t* dst = qcand + ((size_t)(qbase + q) * NSLICE + s) * CAP;
        for (uint32_t e = lane; e < cc; e += 64) dst[e] = qd[q][e];
        if (lane == 0) qcnt[(qbase + q) * NSLICE + s] = c;
    }
}

// ---------- kernel 2: exact merge + loss term — 1 wave per query ----------
__global__ __launch_bounds__(256) void merge_kernel(const float* __restrict__ pred,
                                                    const float* __restrict__ ref,
                                                    const float4* __restrict__ paramsB,
                                                    const uint32_t* __restrict__ qcand,
                                                    const uint32_t* __restrict__ qcnt,
                                                    float* __restrict__ partial) {
    int lane = threadIdx.x & 63;
    int wid  = threadIdx.x >> 6;
    int b = blockIdx.x & 7;
    int g = blockIdx.x >> 3;
    int l = g * 4 + wid;
    int bl = b * 256 + l;

    if (l == 255) {                    // its top-16 feeds only excluded row 0
        if (lane == 0) partial[bl] = 0.0f;
        return;
    }

    uint32_t rc0 = qcnt[bl * 4 + 0], rc1 = qcnt[bl * 4 + 1];
    uint32_t rc2 = qcnt[bl * 4 + 2], rc3 = qcnt[bl * 4 + 3];
    bool ovf = (rc0 > CAP) || (rc1 > CAP) || (rc2 > CAP) || (rc3 > CAP);
    uint32_t o1 = rc0, o2 = rc0 + rc1, o3 = o2 + rc2, U = o3 + rc3;

    float px1 = pred[(size_t)(bl + 1) * 8 + 0];
    float py1 = pred[(size_t)(bl + 1) * 8 + 1];
    float4 pqv = paramsB[bl];
    const float* rb = ref + (size_t)b * 3 * HW;

    float dmin = 3.4e38f, btx = 0.0f, bty = 0.0f;

    if (!ovf && U <= 256) {
        // load candidates (<=4 per lane, static reg names), exact sims, exact keys
        const uint32_t* src = qcand + (size_t)bl * 4 * CAP;
        u64 r0, r1, r2, r3;
        #define LOADJ(jj, rj)                                                   \
        {                                                                       \
            uint32_t e = (jj) * 64 + lane;                                      \
            u64 v = ~0ull;                                                      \
            if (e < U) {                                                        \
                uint32_t ss, off;                                               \
                if (e < o1)      { ss = 0; off = e; }                           \
                else if (e < o2) { ss = 1; off = e - o1; }                      \
                else if (e < o3) { ss = 2; off = e - o2; }                      \
                else             { ss = 3; off = e - o3; }                      \
                uint32_t pidx = src[ss * CAP + off];                            \
                float c0v = rb[pidx], c1v = rb[pidx + HW], c2v = rb[pidx + 2 * HW]; \
                float rs = exact_rsq(c0v, c1v, c2v);                            \
                float sx = exact_sim(c0v, c1v, c2v, rs, pqv);                   \
                v = ((u64)fkey(sx) << 32) | pidx;                               \
            }                                                                   \
            rj = v;                                                             \
        }
        LOADJ(0, r0) LOADJ(1, r1) LOADJ(2, r2) LOADJ(3, r3)
        #undef LOADJ

        // 16 rounds: global min extraction in rank order (keys globally unique)
        #pragma unroll 1
        for (int rnd = 0; rnd < 16; ++rnd) {
            u64 mloc = umin64(umin64(r0, r1), umin64(r2, r3));
            u64 gm = wave_min_u64(mloc);
            LOSS_STEP(gm)
            r0 = (r0 == gm) ? ~0ull : r0;
            r1 = (r1 == gm) ? ~0ull : r1;
            r2 = (r2 == gm) ? ~0ull : r2;
            r3 = (r3 == gm) ? ~0ull : r3;
        }
    } else {
        // safety net (expected never taken): exact full rescan for this query
        u64 kept[KK];
        #pragma unroll
        for (int j = 0; j < KK; ++j) kept[j] = ~0ull;
        const float4* pg = (const float4*)rb;
        #pragma unroll 1
        for (int st = lane; st < SITES; st += 64) {
            float4 a0 = pg[st], a1 = pg[st + SITES], a2 = pg[st + 2 * SITES];
            int base = st * 4;
            #define FB(comp, ei)                                                \
            {                                                                   \
                float rs = exact_rsq(a0.comp, a1.comp, a2.comp);                \
                float sx = exact_sim(a0.comp, a1.comp, a2.comp, rs, pqv);       \
                u64 key = ((u64)fkey(sx) << 32) | (uint32_t)(base + (ei));      \
                if (key < kept[KK - 1]) insert64(kept, key);                    \
            }
            FB(x, 0) FB(y, 1) FB(z, 2) FB(w, 3)
            #undef FB
        }
        #pragma unroll 1
        for (int rnd = 0; rnd < 16; ++rnd) {
            u64 gm = wave_min_u64(kept[0]);
            if (kept[0] == gm) {          // exactly one lane (unique keys)
                #pragma unroll
                for (int j = 0; j < KK - 1; ++j) kept[j] = kept[j + 1];
                kept[KK - 1] = ~0ull;
            }
            LOSS_STEP(gm)
        }
    }

    if (lane == 0) {
        float ex = __fsub_rn(px1, btx);
        float ey = __fsub_rn(py1, bty);
        partial[bl] = __fadd_rn(__fmul_rn(ex, ex), __fmul_rn(ey, ey));
    }
}

// ---------- kernel 3: reduce 2048 partials -> mean ----------
__global__ __launch_bounds__(256) void reduce_kernel(const float* __restrict__ partial,
                                                     float* __restrict__ out) {
    __shared__ double sred[256];
    double a = 0.0;
    #pragma unroll
    for (int i = 0; i < 8; ++i) a += (double)partial[i * 256 + threadIdx.x];
    sred[threadIdx.x] = a;
    __syncthreads();
    for (int s = 128; s > 0; s >>= 1) {
        if (threadIdx.x < s) sred[threadIdx.x] += sred[threadIdx.x + s];
        __syncthreads();
    }
    if (threadIdx.x == 0) out[0] = (float)(sred[0] / 2040.0);
}

// ---------- launch ----------
extern "C" void kernel_launch(void* const* d_in, const int* in_sizes, int n_in,
                              void* d_out, int out_size, void* d_ws, size_t ws_size,
                              hipStream_t stream) {
    const float* pred = (const float*)d_in[0];   // (8,256,8) f32
    const float* ref  = (const float*)d_in[1];   // (8,3,192,192) f32
    float* out = (float*)d_out;

    char* ws = (char*)d_ws;
    float*    partial = (float*)ws;                     //      0 ..   8192
    float4*   paramsA = (float4*)(ws + 8192);           //   8192 ..  40960  (px,py,pz,h)
    float4*   paramsB = (float4*)(ws + 40960);          //  40960 ..  73728  (px,py,pz,psq)
    uint32_t* qcnt    = (uint32_t*)(ws + 73728);        //  73728 .. 106496
    uint32_t* qcand   = (uint32_t*)(ws + 106496);       // 106496 .. +4 MiB

    tau_kernel   <<< 512, 256, 0, stream>>>(pred, ref, paramsA, paramsB);
    scan_kernel  <<<1024, 256, 0, stream>>>(ref, paramsA, qcand, qcnt);
    merge_kernel <<< 512, 256, 0, stream>>>(pred, ref, paramsB, qcand, qcnt, partial);
    reduce_kernel<<<   1, 256, 0, stream>>>(partial, out);
}

// Round 2
// 105.348 us; speedup vs baseline: 1.3766x; 1.1631x over previous
//
#include <hip/hip_runtime.h>
#include <stdint.h>

#define BS 8
#define LQ 256
#define HH 192
#define WW 192
#define HW (HH*WW)          /* 36864 pixels per plane */
#define KK 16
#define SITES 9216          /* float4 sites per plane */
#define SLICE_SITES 2304    /* 4 slices */
#define NSLICE 4
#define CAP 128             /* per (query,slice) candidate capacity */
#define PAD_FILT 4e-5f      /* filter safety: fma-vs-exact error ~1e-6 */

typedef unsigned long long u64;

// ---------- helpers ----------

__device__ __forceinline__ uint32_t fkey(float f) {
    uint32_t u = __float_as_uint(f);
    uint32_t mask = (uint32_t)((int32_t)u >> 31) | 0x80000000u;
    return u ^ mask;
}
__device__ __forceinline__ float inv_fkey(uint32_t v) {
    uint32_t u = (v & 0x80000000u) ? (v ^ 0x80000000u) : ~v;
    return __uint_as_float(u);
}

__device__ __forceinline__ u64 umin64(u64 a, u64 b) { return a < b ? a : b; }

__device__ __forceinline__ u64 wave_min_u64(u64 v) {
    #pragma unroll
    for (int off = 32; off >= 1; off >>= 1) {
        uint32_t lo = (uint32_t)v, hi = (uint32_t)(v >> 32);
        lo = __shfl_xor(lo, off, 64);
        hi = __shfl_xor(hi, off, 64);
        u64 o = ((u64)hi << 32) | lo;
        v = umin64(v, o);
    }
    return v;
}

// sorted ascending insertion, 16 deep (fallback path only)
__device__ __forceinline__ void insert64(u64 (&kept)[KK], u64 key) {
    #pragma unroll
    for (int j = KK - 1; j >= 1; --j) {
        u64 a = kept[j - 1];
        u64 mn = umin64(kept[j], key);
        kept[j] = (key < a) ? a : mn;
    }
    kept[0] = umin64(kept[0], key);
}

// sorted ascending insertion, 4 deep (u32 keys)
__device__ __forceinline__ void insert4(uint32_t (&k)[4], uint32_t key) {
    #pragma unroll
    for (int j = 3; j >= 1; --j) {
        uint32_t a = k[j - 1];
        uint32_t mn = min(k[j], key);
        k[j] = (key < a) ? a : mn;
    }
    k[0] = min(k[0], key);
}

// exact (reference-rounded) similarity pieces — bit-identical to validated kernel
__device__ __forceinline__ float exact_rsq(float a, float b, float c) {
    return __fadd_rn(__fadd_rn(__fmul_rn(a, a), __fmul_rn(b, b)), __fmul_rn(c, c));
}
__device__ __forceinline__ float exact_sim(float c0, float c1, float c2, float rsq, float4 pq) {
    float cr = __fadd_rn(__fadd_rn(__fmul_rn(c0, pq.x), __fmul_rn(c1, pq.y)), __fmul_rn(c2, pq.z));
    return __fadd_rn(__fsub_rn(rsq, __fmul_rn(2.0f, cr)), pq.w);
}

// loss-term tracking for one extracted (rank-ordered) candidate; strict < keeps
// the first (lowest-rank) minimum == jnp.argmin tie-break
#define LOSS_STEP(gmv)                                                   \
{                                                                        \
    uint32_t idxv = (uint32_t)(gmv);                                     \
    float tx = (float)(idxv % WW) / 192.0f;                              \
    float ty = (float)(idxv / WW) / 192.0f;                              \
    float ddx = __fsub_rn(px1, tx);                                      \
    float ddy = __fsub_rn(py1, ty);                                      \
    float dd = __fadd_rn(__fmul_rn(ddx, ddx), __fmul_rn(ddy, ddy));      \
    if (dd < dmin) { dmin = dd; btx = tx; bty = ty; }                    \
}

// ---------- kernel 0: pooled + sound filter threshold ----------
// Block = (image, 4 consecutive queries), 4 waves. Each wave samples 8
// coalesced runs of 64 float4 sites (block total: 8192 px), computes d for
// all 4 queries sharing the rsq term, keeps per-lane top-4 per query.
// Per-query 1024 kept keys -> LDS; wave w binary-search-refines query w.
// h = (lower bound on sample's 16th-largest d_fma) - PAD_FILT: sound since
// sample subset-of image and |d_fma - d_exact| ~1e-6 << PAD_FILT.
__global__ __launch_bounds__(256) void tau_kernel(const float* __restrict__ pred,
                                                  const float* __restrict__ ref,
                                                  float4* __restrict__ paramsA,
                                                  float4* __restrict__ paramsB) {
    __shared__ float4 spool[4];
    __shared__ uint32_t skept[4][1024];   // 16 KB

    int tid  = threadIdx.x;
    int lane = tid & 63;
    int wid  = tid >> 6;
    int b = blockIdx.x & 7;            // XCD swizzle: image b -> XCD b
    int g = blockIdx.x >> 3;           // 0..63
    int l = g * 4 + wid;               // this wave's query, 0..255
    int bl = b * 256 + l;

    // pooled for this wave's query (all lanes redundant; uniform) — verbatim
    // reference rounding
    int i = l * BS + b;                // scrambled flat grid row
    int b2 = i >> 8, l2 = i & 255;
    const float* pr = pred + ((b2 * 256 + l2) * 8);
    float x = pr[0], y = pr[1];
    float fx = rintf(__fsub_rn(__fmul_rn(x, 192.0f), 0.5f));
    float fy = rintf(__fsub_rn(__fmul_rn(y, 192.0f), 0.5f));
    int ix = (int)fx, iy = (int)fy;
    int inb = (ix >= 0 && ix < WW && iy >= 0 && iy < HH) ? 1 : 0;
    int ixc = min(max(ix, 0), WW - 1);
    int iyc = min(max(iy, 0), HH - 1);
    float m = (float)inb;
    const float* img = ref + b * 3 * HW + iyc * WW + ixc;
    float p0 = __fmul_rn(img[0], m);
    float p1 = __fmul_rn(img[HW], m);
    float p2 = __fmul_rn(img[2 * HW], m);
    float psq = __fadd_rn(__fadd_rn(__fmul_rn(p0, p0), __fmul_rn(p1, p1)), __fmul_rn(p2, p2));

    if (lane == 0) spool[wid] = make_float4(p0, p1, p2, psq);
    __syncthreads();
    float px[4], py[4], pz[4];
    #pragma unroll
    for (int q = 0; q < 4; ++q) {
        float4 s = spool[q];
        px[q] = s.x; py[q] = s.y; pz[q] = s.z;
    }

    const float4* p0g = (const float4*)(ref + (size_t)b * 3 * HW);

    uint32_t kept[4][4];
    #pragma unroll
    for (int q = 0; q < 4; ++q)
        #pragma unroll
        for (int j = 0; j < 4; ++j) kept[q][j] = ~0u;

    // 8 coalesced runs per wave: run = wid*8+it, sites run*288 + lane
    int site = (wid * 8) * 288 + lane;
    float4 n0 = p0g[site], n1 = p0g[site + SITES], n2 = p0g[site + 2 * SITES];

    #pragma unroll 1
    for (int it = 0; it < 8; ++it) {
        float4 a0 = n0, a1 = n1, a2 = n2;
        int sn = (it < 7) ? (site + 288) : site;
        n0 = p0g[sn]; n1 = p0g[sn + SITES]; n2 = p0g[sn + 2 * SITES];

        #define SAMP(comp)                                                              \
        {                                                                               \
            float nr = -0.5f * fmaf(a2.comp, a2.comp, fmaf(a1.comp, a1.comp,            \
                              a0.comp * a0.comp));                                      \
            _Pragma("unroll")                                                           \
            for (int q = 0; q < 4; ++q) {                                               \
                float d = fmaf(a2.comp, pz[q], fmaf(a1.comp, py[q],                     \
                               fmaf(a0.comp, px[q], nr)));                              \
                uint32_t k = fkey(-d);                                                  \
                if (k < kept[q][3]) insert4(kept[q], k);                                \
            }                                                                           \
        }
        SAMP(x) SAMP(y) SAMP(z) SAMP(w)
        #undef SAMP
        site = sn;
    }

    // stash kept -> LDS (conflict-free: lanes consecutive)
    #pragma unroll
    for (int q = 0; q < 4; ++q)
        #pragma unroll
        for (int j = 0; j < 4; ++j)
            skept[q][j * 256 + tid] = kept[q][j];
    __syncthreads();

    // wave wid refines its own query over the block's 1024 kept keys.
    // invariant count(vals <= hi) >= 16 kept at every step -> hi >= 16th
    // smallest key -> h is a sound (possibly looser) bound.
    uint32_t vals[16];
    #pragma unroll
    for (int j = 0; j < 16; ++j) vals[j] = skept[wid][j * 64 + lane];
    uint32_t lo = 0x00800000u, hi = 0xFF7FFFFFu;
    #pragma unroll 1
    for (int t = 0; t < 24; ++t) {
        uint32_t mid = lo + ((hi - lo) >> 1);
        int c = 0;
        #pragma unroll
        for (int j = 0; j < 16; ++j) c += (vals[j] <= mid) ? 1 : 0;
        #pragma unroll
        for (int off = 32; off >= 1; off >>= 1) c += __shfl_xor(c, off, 64);
        if (c >= KK) hi = mid; else lo = mid + 1;
    }
    float h = -inv_fkey(hi) - PAD_FILT;

    if (lane == 0) {
        paramsA[bl] = make_float4(p0, p1, p2, h);
        paramsB[bl] = make_float4(p0, p1, p2, psq);
    }
}

// ---------- kernel 1: shared scan — block = (image, 8 queries, 1/4 image) ----------
__global__ __launch_bounds__(256) void scan_kernel(const float* __restrict__ ref,
                                                   const float4* __restrict__ paramsA,
                                                   uint32_t* __restrict__ qcand,
                                                   uint32_t* __restrict__ qcnt) {
    __shared__ uint32_t qd[8][CAP];   // 4 KB
    __shared__ uint32_t cnt[8];

    int tid  = threadIdx.x;
    int lane = tid & 63;
    int wid  = tid >> 6;
    int b  = blockIdx.x & 7;          // XCD swizzle
    int r  = blockIdx.x >> 3;         // 0..127
    int qg = r & 31;                  // query group (8 queries)
    int s  = r >> 5;                  // slice 0..3
    int qbase = b * 256 + qg * 8;

    if (tid < 8) cnt[tid] = 0;

    // per-query filter params: wave-uniform -> scalar loads / SGPRs
    float px[8], py[8], pz[8], hh[8];
    #pragma unroll
    for (int q = 0; q < 8; ++q) {
        float4 pa = paramsA[qbase + q];
        px[q] = pa.x; py[q] = pa.y; pz[q] = pa.z; hh[q] = pa.w;
    }
    __syncthreads();

    const float4* p0g = (const float4*)(ref + (size_t)b * 3 * HW);
    int site = s * SLICE_SITES + tid;
    float4 n0 = p0g[site], n1 = p0g[site + SITES], n2 = p0g[site + 2 * SITES];

    #pragma unroll 1
    for (int it = 0; it < 9; ++it) {           // 9 * 256 sites = one slice
        float4 a0 = n0, a1 = n1, a2 = n2;
        int sn = (it < 8) ? (site + 256) : site;   // clamp last prefetch (stay in-bounds)
        n0 = p0g[sn]; n1 = p0g[sn + SITES]; n2 = p0g[sn + 2 * SITES];
        int base = site * 4;

        // shared across all 8 queries: -0.5*||ref||^2 per component
        float nrx = -0.5f * fmaf(a2.x, a2.x, fmaf(a1.x, a1.x, a0.x * a0.x));
        float nry = -0.5f * fmaf(a2.y, a2.y, fmaf(a1.y, a1.y, a0.y * a0.y));
        float nrz = -0.5f * fmaf(a2.z, a2.z, fmaf(a1.z, a1.z, a0.z * a0.z));
        float nrw = -0.5f * fmaf(a2.w, a2.w, fmaf(a1.w, a1.w, a0.w * a0.w));

        #pragma unroll
        for (int q = 0; q < 8; ++q) {
            float dx = fmaf(a2.x, pz[q], fmaf(a1.x, py[q], fmaf(a0.x, px[q], nrx)));
            float dy = fmaf(a2.y, pz[q], fmaf(a1.y, py[q], fmaf(a0.y, px[q], nry)));
            float dz = fmaf(a2.z, pz[q], fmaf(a1.z, py[q], fmaf(a0.z, px[q], nrz)));
            float dw = fmaf(a2.w, pz[q], fmaf(a1.w, py[q], fmaf(a0.w, px[q], nrw)));
            bool g0 = dx >= hh[q];
            bool g1 = dy >= hh[q];
            bool g2 = dz >= hh[q];
            bool g3 = dw >= hh[q];
            if (__ballot(g0 | g1 | g2 | g3)) {
                #define PUSHI(gc, ei)                                          \
                if (gc) {                                                      \
                    uint32_t slot = atomicAdd(&cnt[q], 1u);                    \
                    if (slot < CAP) qd[q][slot] = (uint32_t)(base + ei);       \
                }
                PUSHI(g0, 0) PUSHI(g1, 1) PUSHI(g2, 2) PUSHI(g3, 3)
                #undef PUSHI
            }
        }
        site += 256;
    }
    __syncthreads();

    // write queues to global (raw count preserved as overflow signal)
    for (int q = wid; q < 8; q += 4) {
        uint32_t c  = cnt[q];
        uint32_t cc = c < CAP ? c : CAP;
        uint32_t* dst = qcand + ((size_t)(qbase + q) * NSLICE + s) * CAP;
        for (uint32_t e = lane; e < cc; e += 64) dst[e] = qd[q][e];
        if (lane == 0) qcnt[(qbase + q) * NSLICE + s] = c;
    }
}

// ---------- kernel 2: exact merge + loss term — 1 wave per query ----------
__global__ __launch_bounds__(256) void merge_kernel(const float* __restrict__ pred,
                                                    const float* __restrict__ ref,
                                                    const float4* __restrict__ paramsB,
                                                    const uint32_t* __restrict__ qcand,
                                                    const uint32_t* __restrict__ qcnt,
                                                    float* __restrict__ partial) {
    int lane = threadIdx.x & 63;
    int wid  = threadIdx.x >> 6;
    int b = blockIdx.x & 7;
    int g = blockIdx.x >> 3;
    int l = g * 4 + wid;
    int bl = b * 256 + l;

    if (l == 255) {                    // its top-16 feeds only excluded row 0
        if (lane == 0) partial[bl] = 0.0f;
        return;
    }

    uint32_t rc0 = qcnt[bl * 4 + 0], rc1 = qcnt[bl * 4 + 1];
    uint32_t rc2 = qcnt[bl * 4 + 2], rc3 = qcnt[bl * 4 + 3];
    bool ovf = (rc0 > CAP) || (rc1 > CAP) || (rc2 > CAP) || (rc3 > CAP);
    uint32_t o1 = rc0, o2 = rc0 + rc1, o3 = o2 + rc2, U = o3 + rc3;

    float px1 = pred[(size_t)(bl + 1) * 8 + 0];
    float py1 = pred[(size_t)(bl + 1) * 8 + 1];
    float4 pqv = paramsB[bl];
    const float* rb = ref + (size_t)b * 3 * HW;

    float dmin = 3.4e38f, btx = 0.0f, bty = 0.0f;

    if (!ovf && U <= 256) {
        // load candidates (<=4 per lane, static reg names), exact sims, exact keys
        const uint32_t* src = qcand + (size_t)bl * 4 * CAP;
        u64 r0, r1, r2, r3;
        #define LOADJ(jj, rj)                                                   \
        {                                                                       \
            uint32_t e = (jj) * 64 + lane;                                      \
            u64 v = ~0ull;                                                      \
            if (e < U) {                                                        \
                uint32_t ss, off;                                               \
                if (e < o1)      { ss = 0; off = e; }                           \
                else if (e < o2) { ss = 1; off = e - o1; }                      \
                else if (e < o3) { ss = 2; off = e - o2; }                      \
                else             { ss = 3; off = e - o3; }                      \
                uint32_t pidx = src[ss * CAP + off];                            \
                float c0v = rb[pidx], c1v = rb[pidx + HW], c2v = rb[pidx + 2 * HW]; \
                float rs = exact_rsq(c0v, c1v, c2v);                            \
                float sx = exact_sim(c0v, c1v, c2v, rs, pqv);                   \
                v = ((u64)fkey(sx) << 32) | pidx;                               \
            }                                                                   \
            rj = v;                                                             \
        }
        LOADJ(0, r0) LOADJ(1, r1) LOADJ(2, r2) LOADJ(3, r3)
        #undef LOADJ

        // 16 rounds: global min extraction in rank order (keys globally unique)
        #pragma unroll 1
        for (int rnd = 0; rnd < 16; ++rnd) {
            u64 mloc = umin64(umin64(r0, r1), umin64(r2, r3));
            u64 gm = wave_min_u64(mloc);
            LOSS_STEP(gm)
            r0 = (r0 == gm) ? ~0ull : r0;
            r1 = (r1 == gm) ? ~0ull : r1;
            r2 = (r2 == gm) ? ~0ull : r2;
            r3 = (r3 == gm) ? ~0ull : r3;
        }
    } else {
        // safety net (expected never taken): exact full rescan for this query
        u64 kept[KK];
        #pragma unroll
        for (int j = 0; j < KK; ++j) kept[j] = ~0ull;
        const float4* pg = (const float4*)rb;
        #pragma unroll 1
        for (int st = lane; st < SITES; st += 64) {
            float4 a0 = pg[st], a1 = pg[st + SITES], a2 = pg[st + 2 * SITES];
            int base = st * 4;
            #define FB(comp, ei)                                                \
            {                                                                   \
                float rs = exact_rsq(a0.comp, a1.comp, a2.comp);                \
                float sx = exact_sim(a0.comp, a1.comp, a2.comp, rs, pqv);       \
                u64 key = ((u64)fkey(sx) << 32) | (uint32_t)(base + (ei));      \
                if (key < kept[KK - 1]) insert64(kept, key);                    \
            }
            FB(x, 0) FB(y, 1) FB(z, 2) FB(w, 3)
            #undef FB
        }
        #pragma unroll 1
        for (int rnd = 0; rnd < 16; ++rnd) {
            u64 gm = wave_min_u64(kept[0]);
            if (kept[0] == gm) {          // exactly one lane (unique keys)
                #pragma unroll
                for (int j = 0; j < KK - 1; ++j) kept[j] = kept[j + 1];
                kept[KK - 1] = ~0ull;
            }
            LOSS_STEP(gm)
        }
    }

    if (lane == 0) {
        float ex = __fsub_rn(px1, btx);
        float ey = __fsub_rn(py1, bty);
        partial[bl] = __fadd_rn(__fmul_rn(ex, ex), __fmul_rn(ey, ey));
    }
}

// ---------- kernel 3: reduce 2048 partials -> mean ----------
__global__ __launch_bounds__(256) void reduce_kernel(const float* __restrict__ partial,
                                                     float* __restrict__ out) {
    __shared__ double sred[256];
    double a = 0.0;
    #pragma unroll
    for (int i = 0; i < 8; ++i) a += (double)partial[i * 256 + threadIdx.x];
    sred[threadIdx.x] = a;
    __syncthreads();
    for (int s = 128; s > 0; s >>= 1) {
        if (threadIdx.x < s) sred[threadIdx.x] += sred[threadIdx.x + s];
        __syncthreads();
    }
    if (threadIdx.x == 0) out[0] = (float)(sred[0] / 2040.0);
}

// ---------- launch ----------
extern "C" void kernel_launch(void* const* d_in, const int* in_sizes, int n_in,
                              void* d_out, int out_size, void* d_ws, size_t ws_size,
                              hipStream_t stream) {
    const float* pred = (const float*)d_in[0];   // (8,256,8) f32
    const float* ref  = (const float*)d_in[1];   // (8,3,192,192) f32
    float* out = (float*)d_out;

    char* ws = (char*)d_ws;
    float*    partial = (float*)ws;                     //      0 ..   8192
    float4*   paramsA = (float4*)(ws + 8192);           //   8192 ..  40960  (px,py,pz,h)
    float4*   paramsB = (float4*)(ws + 40960);          //  40960 ..  73728  (px,py,pz,psq)
    uint32_t* qcnt    = (uint32_t*)(ws + 73728);        //  73728 .. 106496
    uint32_t* qcand   = (uint32_t*)(ws + 106496);       // 106496 .. +4 MiB

    tau_kernel   <<< 512, 256, 0, stream>>>(pred, ref, paramsA, paramsB);
    scan_kernel  <<<1024, 256, 0, stream>>>(ref, paramsA, qcand, qcnt);
    merge_kernel <<< 512, 256, 0, stream>>>(pred, ref, paramsB, qcand, qcnt, partial);
    reduce_kernel<<<   1, 256, 0, stream>>>(partial, out);
}

// Round 3
// 102.186 us; speedup vs baseline: 1.4192x; 1.0309x over previous
//
#include <hip/hip_runtime.h>
#include <stdint.h>

#define BS 8
#define HH 192
#define WW 192
#define HW (HH*WW)          /* 36864 pixels per plane */
#define KK 16
#define SITES 9216          /* float4 sites per plane */
#define QCAP 512            /* per-query candidate capacity (E[U] ~ 144) */
#define PAD_FILT 4e-5f      /* filter safety: fma-vs-exact error ~1e-6 */

typedef unsigned long long u64;

// ---------- helpers ----------

__device__ __forceinline__ uint32_t fkey(float f) {
    uint32_t u = __float_as_uint(f);
    uint32_t mask = (uint32_t)((int32_t)u >> 31) | 0x80000000u;
    return u ^ mask;
}
__device__ __forceinline__ float inv_fkey(uint32_t v) {
    uint32_t u = (v & 0x80000000u) ? (v ^ 0x80000000u) : ~v;
    return __uint_as_float(u);
}

__device__ __forceinline__ u64 umin64(u64 a, u64 b) { return a < b ? a : b; }

__device__ __forceinline__ u64 wave_min_u64(u64 v) {
    #pragma unroll
    for (int off = 32; off >= 1; off >>= 1) {
        uint32_t lo = (uint32_t)v, hi = (uint32_t)(v >> 32);
        lo = __shfl_xor(lo, off, 64);
        hi = __shfl_xor(hi, off, 64);
        u64 o = ((u64)hi << 32) | lo;
        v = umin64(v, o);
    }
    return v;
}

// sorted ascending insertion, 16 deep (fallback path only)
__device__ __forceinline__ void insert64(u64 (&kept)[KK], u64 key) {
    #pragma unroll
    for (int j = KK - 1; j >= 1; --j) {
        u64 a = kept[j - 1];
        u64 mn = umin64(kept[j], key);
        kept[j] = (key < a) ? a : mn;
    }
    kept[0] = umin64(kept[0], key);
}

// sorted ascending insertion, 4 deep (u32 keys)
__device__ __forceinline__ void insert4(uint32_t (&k)[4], uint32_t key) {
    #pragma unroll
    for (int j = 3; j >= 1; --j) {
        uint32_t a = k[j - 1];
        uint32_t mn = min(k[j], key);
        k[j] = (key < a) ? a : mn;
    }
    k[0] = min(k[0], key);
}

// exact (reference-rounded) similarity pieces — bit-identical to validated kernel
__device__ __forceinline__ float exact_rsq(float a, float b, float c) {
    return __fadd_rn(__fadd_rn(__fmul_rn(a, a), __fmul_rn(b, b)), __fmul_rn(c, c));
}
__device__ __forceinline__ float exact_sim(float c0, float c1, float c2, float rsq, float4 pq) {
    float cr = __fadd_rn(__fadd_rn(__fmul_rn(c0, pq.x), __fmul_rn(c1, pq.y)), __fmul_rn(c2, pq.z));
    return __fadd_rn(__fsub_rn(rsq, __fmul_rn(2.0f, cr)), pq.w);
}

// loss-term tracking for one extracted (rank-ordered) candidate; strict < keeps
// the first (lowest-rank) minimum == jnp.argmin tie-break
#define LOSS_STEP(gmv)                                                   \
{                                                                        \
    uint32_t idxv = (uint32_t)(gmv);                                     \
    float tx = (float)(idxv % WW) / 192.0f;                              \
    float ty = (float)(idxv / WW) / 192.0f;                              \
    float ddx = __fsub_rn(px1, tx);                                      \
    float ddy = __fsub_rn(py1, ty);                                      \
    float dd = __fadd_rn(__fmul_rn(ddx, ddx), __fmul_rn(ddy, ddy));      \
    if (dd < dmin) { dmin = dd; btx = tx; bty = ty; }                    \
}

// ---------- fused kernel: block = (image, 8 queries), 1024 threads ----------
// Phase 0: pooled/psq per query (exact, verbatim reference rounding)
// Phase 1: sample — thread t evaluates 8 coalesced sites for query t&7,
//          keeps per-lane top-4 d-keys (4096 px sampled per query)
// Phase 2: waves 0..7 binary-search a sound per-query threshold h
//          (sample subset-of image => h <= true 16th-best d; PAD covers
//          the ~1e-6 fma-vs-exact discrepancy)
// Phase 3: all waves scan the full image once; shared -0.5*rsq across the
//          8 queries; passing pixel indices -> per-query LDS queue
// Phase 4: waves 0..7 — exact sims for candidates, 16-round unique-key
//          min extraction (reference rank order), argmin/loss epilogue
__global__ __launch_bounds__(1024) void fused_kernel(const float* __restrict__ pred,
                                                     const float* __restrict__ ref,
                                                     float* __restrict__ partial) {
    __shared__ uint32_t smem[8][QCAP];   // 16 KB: skept (ph1-2), then qd (ph3-4)
    __shared__ float4 spool[8];
    __shared__ float sh[8];
    __shared__ uint32_t cnt[8];

    int tid  = threadIdx.x;
    int lane = tid & 63;
    int wid  = tid >> 6;              // 0..15
    int b  = blockIdx.x & 7;          // XCD swizzle: image b -> XCD b
    int qg = blockIdx.x >> 3;         // 0..31

    // ---- phase 0: pooled for the block's 8 queries ----
    if (tid < 8) {
        int l = qg * 8 + tid;
        int i = l * BS + b;           // scrambled flat grid row
        int b2 = i >> 8, l2 = i & 255;
        const float* pr = pred + ((b2 * 256 + l2) * 8);
        float x = pr[0], y = pr[1];
        float fx = rintf(__fsub_rn(__fmul_rn(x, 192.0f), 0.5f));
        float fy = rintf(__fsub_rn(__fmul_rn(y, 192.0f), 0.5f));
        int ix = (int)fx, iy = (int)fy;
        int inb = (ix >= 0 && ix < WW && iy >= 0 && iy < HH) ? 1 : 0;
        int ixc = min(max(ix, 0), WW - 1);
        int iyc = min(max(iy, 0), HH - 1);
        float m = (float)inb;
        const float* img = ref + b * 3 * HW + iyc * WW + ixc;
        float p0 = __fmul_rn(img[0], m);
        float p1 = __fmul_rn(img[HW], m);
        float p2 = __fmul_rn(img[2 * HW], m);
        float psq = __fadd_rn(__fadd_rn(__fmul_rn(p0, p0), __fmul_rn(p1, p1)),
                              __fmul_rn(p2, p2));
        spool[tid] = make_float4(p0, p1, p2, psq);
        cnt[tid] = 0;
    }
    __syncthreads();

    const float4* p0g = (const float4*)(ref + (size_t)b * 3 * HW);
    int myq = tid & 7;
    float4 sp = spool[myq];           // conflict-free broadcast read

    // ---- phase 1: sample (sites t + k*1024, k=0..7 — coalesced) ----
    uint32_t kept[4] = {~0u, ~0u, ~0u, ~0u};
    {
        int site = tid;
        float4 n0 = p0g[site], n1 = p0g[site + SITES], n2 = p0g[site + 2 * SITES];
        #pragma unroll 1
        for (int it = 0; it < 8; ++it) {
            float4 a0 = n0, a1 = n1, a2 = n2;
            int sn = (it < 7) ? (site + 1024) : site;
            n0 = p0g[sn]; n1 = p0g[sn + SITES]; n2 = p0g[sn + 2 * SITES];
            #define SAMP1(comp)                                                         \
            {                                                                           \
                float nr = -0.5f * fmaf(a2.comp, a2.comp, fmaf(a1.comp, a1.comp,        \
                                  a0.comp * a0.comp));                                  \
                float d  = fmaf(a2.comp, sp.z, fmaf(a1.comp, sp.y,                      \
                               fmaf(a0.comp, sp.x, nr)));                               \
                uint32_t k = fkey(-d);                                                  \
                if (k < kept[3]) insert4(kept, k);                                      \
            }
            SAMP1(x) SAMP1(y) SAMP1(z) SAMP1(w)
            #undef SAMP1
            site = sn;
        }
    }
    {
        int slot = (tid >> 3) * 4;    // 128 threads/query * 4 keys = 512
        smem[myq][slot + 0] = kept[0];
        smem[myq][slot + 1] = kept[1];
        smem[myq][slot + 2] = kept[2];
        smem[myq][slot + 3] = kept[3];
    }
    __syncthreads();

    // ---- phase 2: per-query threshold (waves 0..7; wave w -> query w) ----
    if (wid < 8) {
        uint32_t vals[8];
        #pragma unroll
        for (int j = 0; j < 8; ++j) vals[j] = smem[wid][j * 64 + lane];
        uint32_t lo = 0x00800000u, hi = 0xFF7FFFFFu;
        #pragma unroll 1
        for (int t = 0; t < 24; ++t) {
            uint32_t mid = lo + ((hi - lo) >> 1);
            int c = 0;
            #pragma unroll
            for (int j = 0; j < 8; ++j) c += (vals[j] <= mid) ? 1 : 0;
            #pragma unroll
            for (int off = 32; off >= 1; off >>= 1) c += __shfl_xor(c, off, 64);
            if (c >= KK) hi = mid; else lo = mid + 1;
        }
        float hval = -inv_fkey(hi) - PAD_FILT;
        if (qg == 31 && wid == 7) hval = 3.0e38f;   // l==255: never pass
        if (lane == 0) sh[wid] = hval;
    }
    __syncthreads();

    // ---- phase 3: full-image scan, 8 queries share rsq ----
    float px[8], py[8], pz[8], hh[8];
    #pragma unroll
    for (int q = 0; q < 8; ++q) {
        float4 s = spool[q];
        px[q] = s.x; py[q] = s.y; pz[q] = s.z; hh[q] = sh[q];
    }

    {
        int site = tid;
        float4 n0 = p0g[site], n1 = p0g[site + SITES], n2 = p0g[site + 2 * SITES];
        #pragma unroll 1
        for (int it = 0; it < 9; ++it) {       // 9*1024 = 9216 sites
            float4 a0 = n0, a1 = n1, a2 = n2;
            int sn = (it < 8) ? (site + 1024) : site;
            n0 = p0g[sn]; n1 = p0g[sn + SITES]; n2 = p0g[sn + 2 * SITES];
            int base = site * 4;

            float nrx = -0.5f * fmaf(a2.x, a2.x, fmaf(a1.x, a1.x, a0.x * a0.x));
            float nry = -0.5f * fmaf(a2.y, a2.y, fmaf(a1.y, a1.y, a0.y * a0.y));
            float nrz = -0.5f * fmaf(a2.z, a2.z, fmaf(a1.z, a1.z, a0.z * a0.z));
            float nrw = -0.5f * fmaf(a2.w, a2.w, fmaf(a1.w, a1.w, a0.w * a0.w));

            #pragma unroll
            for (int q = 0; q < 8; ++q) {
                float dx = fmaf(a2.x, pz[q], fmaf(a1.x, py[q], fmaf(a0.x, px[q], nrx)));
                float dy = fmaf(a2.y, pz[q], fmaf(a1.y, py[q], fmaf(a0.y, px[q], nry)));
                float dz = fmaf(a2.z, pz[q], fmaf(a1.z, py[q], fmaf(a0.z, px[q], nrz)));
                float dw = fmaf(a2.w, pz[q], fmaf(a1.w, py[q], fmaf(a0.w, px[q], nrw)));
                bool g0 = dx >= hh[q];
                bool g1 = dy >= hh[q];
                bool g2 = dz >= hh[q];
                bool g3 = dw >= hh[q];
                if (__ballot(g0 | g1 | g2 | g3)) {
                    #define PUSHI(gc, ei)                                          \
                    if (gc) {                                                      \
                        uint32_t slot = atomicAdd(&cnt[q], 1u);                    \
                        if (slot < QCAP) smem[q][slot] = (uint32_t)(base + ei);    \
                    }
                    PUSHI(g0, 0) PUSHI(g1, 1) PUSHI(g2, 2) PUSHI(g3, 3)
                    #undef PUSHI
                }
            }
            site = sn;
        }
    }
    __syncthreads();

    // ---- phase 4: exact selection + loss (waves 0..7; wave w -> query w) ----
    if (wid < 8) {
        int l  = qg * 8 + wid;
        int bl = b * 256 + l;
        if (l == 255) {                    // excluded row
            if (lane == 0) partial[bl] = 0.0f;
        } else {
            uint32_t U = cnt[wid];
            float px1 = pred[(size_t)(bl + 1) * 8 + 0];
            float py1 = pred[(size_t)(bl + 1) * 8 + 1];
            float4 pqv = spool[wid];
            const float* rb = ref + (size_t)b * 3 * HW;
            float dmin = 3.4e38f, btx = 0.0f, bty = 0.0f;

            if (U <= QCAP) {
                u64 r0, r1, r2, r3, r4, r5, r6, r7;
                #define LOADJ(jj, rj)                                                   \
                {                                                                       \
                    uint32_t e = (jj) * 64 + lane;                                      \
                    u64 v = ~0ull;                                                      \
                    if (e < U) {                                                        \
                        uint32_t pidx = smem[wid][e];                                   \
                        float c0v = rb[pidx], c1v = rb[pidx + HW], c2v = rb[pidx + 2 * HW]; \
                        float rs = exact_rsq(c0v, c1v, c2v);                            \
                        float sx = exact_sim(c0v, c1v, c2v, rs, pqv);                   \
                        v = ((u64)fkey(sx) << 32) | pidx;                               \
                    }                                                                   \
                    rj = v;                                                             \
                }
                LOADJ(0, r0) LOADJ(1, r1) LOADJ(2, r2) LOADJ(3, r3)
                LOADJ(4, r4) LOADJ(5, r5) LOADJ(6, r6) LOADJ(7, r7)
                #undef LOADJ

                #pragma unroll 1
                for (int rnd = 0; rnd < 16; ++rnd) {
                    u64 mloc = umin64(umin64(umin64(r0, r1), umin64(r2, r3)),
                                      umin64(umin64(r4, r5), umin64(r6, r7)));
                    u64 gm = wave_min_u64(mloc);
                    if (gm != ~0ull) LOSS_STEP(gm)
                    r0 = (r0 == gm) ? ~0ull : r0;
                    r1 = (r1 == gm) ? ~0ull : r1;
                    r2 = (r2 == gm) ? ~0ull : r2;
                    r3 = (r3 == gm) ? ~0ull : r3;
                    r4 = (r4 == gm) ? ~0ull : r4;
                    r5 = (r5 == gm) ? ~0ull : r5;
                    r6 = (r6 == gm) ? ~0ull : r6;
                    r7 = (r7 == gm) ? ~0ull : r7;
                }
            } else {
                // safety net (P ~ 1e-12): exact full rescan for this query
                u64 kept16[KK];
                #pragma unroll
                for (int j = 0; j < KK; ++j) kept16[j] = ~0ull;
                const float4* pg = (const float4*)rb;
                #pragma unroll 1
                for (int st = lane; st < SITES; st += 64) {
                    float4 a0 = pg[st], a1 = pg[st + SITES], a2 = pg[st + 2 * SITES];
                    int base = st * 4;
                    #define FB(comp, ei)                                                \
                    {                                                                   \
                        float rs = exact_rsq(a0.comp, a1.comp, a2.comp);                \
                        float sx = exact_sim(a0.comp, a1.comp, a2.comp, rs, pqv);       \
                        u64 key = ((u64)fkey(sx) << 32) | (uint32_t)(base + (ei));      \
                        if (key < kept16[KK - 1]) insert64(kept16, key);                \
                    }
                    FB(x, 0) FB(y, 1) FB(z, 2) FB(w, 3)
                    #undef FB
                }
                #pragma unroll 1
                for (int rnd = 0; rnd < 16; ++rnd) {
                    u64 gm = wave_min_u64(kept16[0]);
                    if (kept16[0] == gm) {        // exactly one lane (unique keys)
                        #pragma unroll
                        for (int j = 0; j < KK - 1; ++j) kept16[j] = kept16[j + 1];
                        kept16[KK - 1] = ~0ull;
                    }
                    LOSS_STEP(gm)
                }
            }

            if (lane == 0) {
                float ex = __fsub_rn(px1, btx);
                float ey = __fsub_rn(py1, bty);
                partial[bl] = __fadd_rn(__fmul_rn(ex, ex), __fmul_rn(ey, ey));
            }
        }
    }
}

// ---------- reduce 2048 partials -> mean ----------
__global__ __launch_bounds__(256) void reduce_kernel(const float* __restrict__ partial,
                                                     float* __restrict__ out) {
    __shared__ double sred[256];
    double a = 0.0;
    #pragma unroll
    for (int i = 0; i < 8; ++i) a += (double)partial[i * 256 + threadIdx.x];
    sred[threadIdx.x] = a;
    __syncthreads();
    for (int s = 128; s > 0; s >>= 1) {
        if (threadIdx.x < s) sred[threadIdx.x] += sred[threadIdx.x + s];
        __syncthreads();
    }
    if (threadIdx.x == 0) out[0] = (float)(sred[0] / 2040.0);
}

// ---------- launch ----------
extern "C" void kernel_launch(void* const* d_in, const int* in_sizes, int n_in,
                              void* d_out, int out_size, void* d_ws, size_t ws_size,
                              hipStream_t stream) {
    const float* pred = (const float*)d_in[0];   // (8,256,8) f32
    const float* ref  = (const float*)d_in[1];   // (8,3,192,192) f32
    float* out = (float*)d_out;

    float* partial = (float*)d_ws;               // 2048 floats, fully overwritten

    fused_kernel <<<256, 1024, 0, stream>>>(pred, ref, partial);
    reduce_kernel<<<  1,  256, 0, stream>>>(partial, out);
}

// Round 4
// 100.239 us; speedup vs baseline: 1.4467x; 1.0194x over previous
//
#include <hip/hip_runtime.h>
#include <stdint.h>

#define BS 8
#define HH 192
#define WW 192
#define HW (HH*WW)          /* 36864 pixels per plane */
#define KK 16
#define SITES 9216          /* float4 sites per plane */
#define NW 16               /* waves per block */
#define SEGSZ 64            /* per-(query,wave) segment capacity; E ~ 12 */
#define UCAP 512            /* per-query merged candidate cap (8 regs/lane) */
#define PAD_FILT 4e-5f      /* filter safety: fma-vs-exact error ~1e-6 */

typedef unsigned long long u64;

// ---------- helpers ----------

__device__ __forceinline__ uint32_t fkey(float f) {
    uint32_t u = __float_as_uint(f);
    uint32_t mask = (uint32_t)((int32_t)u >> 31) | 0x80000000u;
    return u ^ mask;
}
__device__ __forceinline__ float inv_fkey(uint32_t v) {
    uint32_t u = (v & 0x80000000u) ? (v ^ 0x80000000u) : ~v;
    return __uint_as_float(u);
}

__device__ __forceinline__ u64 umin64(u64 a, u64 b) { return a < b ? a : b; }

__device__ __forceinline__ uint32_t mbcnt64(u64 m) {
    return __builtin_amdgcn_mbcnt_hi((uint32_t)(m >> 32),
            __builtin_amdgcn_mbcnt_lo((uint32_t)m, 0));
}

__device__ __forceinline__ u64 wave_min_u64(u64 v) {
    #pragma unroll
    for (int off = 32; off >= 1; off >>= 1) {
        uint32_t lo = (uint32_t)v, hi = (uint32_t)(v >> 32);
        lo = __shfl_xor(lo, off, 64);
        hi = __shfl_xor(hi, off, 64);
        u64 o = ((u64)hi << 32) | lo;
        v = umin64(v, o);
    }
    return v;
}

// sorted ascending insertion, 16 deep (fallback path only)
__device__ __forceinline__ void insert64(u64 (&kept)[KK], u64 key) {
    #pragma unroll
    for (int j = KK - 1; j >= 1; --j) {
        u64 a = kept[j - 1];
        u64 mn = umin64(kept[j], key);
        kept[j] = (key < a) ? a : mn;
    }
    kept[0] = umin64(kept[0], key);
}

// exact (reference-rounded) similarity pieces — bit-identical to validated kernel
__device__ __forceinline__ float exact_rsq(float a, float b, float c) {
    return __fadd_rn(__fadd_rn(__fmul_rn(a, a), __fmul_rn(b, b)), __fmul_rn(c, c));
}
__device__ __forceinline__ float exact_sim(float c0, float c1, float c2, float rsq, float4 pq) {
    float cr = __fadd_rn(__fadd_rn(__fmul_rn(c0, pq.x), __fmul_rn(c1, pq.y)), __fmul_rn(c2, pq.z));
    return __fadd_rn(__fsub_rn(rsq, __fmul_rn(2.0f, cr)), pq.w);
}

// loss-term tracking for one extracted (rank-ordered) candidate; strict < keeps
// the first (lowest-rank) minimum == jnp.argmin tie-break
#define LOSS_STEP(gmv)                                                   \
{                                                                        \
    uint32_t idxv = (uint32_t)(gmv);                                     \
    float tx = (float)(idxv % WW) / 192.0f;                              \
    float ty = (float)(idxv / WW) / 192.0f;                              \
    float ddx = __fsub_rn(px1, tx);                                      \
    float ddy = __fsub_rn(py1, ty);                                      \
    float dd = __fadd_rn(__fmul_rn(ddx, ddx), __fmul_rn(ddy, ddy));      \
    if (dd < dmin) { dmin = dd; btx = tx; bty = ty; }                    \
}

// ---------- fused kernel: block = (image, 8 queries), 1024 threads ----------
// Phase 0: pooled/psq per query (exact, verbatim reference rounding)
// Phase 1: sample — thread t evaluates 8 coalesced sites for query t&7,
//          tracking per-thread MAX d only (sound: the 16th-largest of the
//          128 per-thread maxima <= sample 16th-largest <= image 16th-largest)
// Phase 2: waves 0..7 binary-search the per-query threshold h
// Phase 3: all waves scan the full image once; shared -0.5*rsq across the
//          8 queries; passing pixel indices -> PRIVATE per-(query,wave) LDS
//          segment via ballot+mbcnt rank (no atomics, scalar counts)
// Phase 4: waves 0..7 — compact the 16 segments, exact sims, 16-round
//          unique-key min extraction (reference rank order), loss epilogue
__global__ __launch_bounds__(1024) void fused_kernel(const float* __restrict__ pred,
                                                     const float* __restrict__ ref,
                                                     float* __restrict__ partial) {
    __shared__ uint32_t seg[8 * NW * SEGSZ];   // 32 KB (also phase-1 key store)
    __shared__ uint32_t compactb[8 * UCAP];    // 16 KB
    __shared__ uint32_t scnts[8 * NW];
    __shared__ float4 spool[8];
    __shared__ float sh[8];

    int tid  = threadIdx.x;
    int lane = tid & 63;
    int wid  = tid >> 6;              // 0..15
    int b  = blockIdx.x & 7;          // XCD swizzle: image b -> XCD b
    int qg = blockIdx.x >> 3;         // 0..31

    // ---- phase 0: pooled for the block's 8 queries ----
    if (tid < 8) {
        int l = qg * 8 + tid;
        int i = l * BS + b;           // scrambled flat grid row
        int b2 = i >> 8, l2 = i & 255;
        const float* pr = pred + ((b2 * 256 + l2) * 8);
        float x = pr[0], y = pr[1];
        float fx = rintf(__fsub_rn(__fmul_rn(x, 192.0f), 0.5f));
        float fy = rintf(__fsub_rn(__fmul_rn(y, 192.0f), 0.5f));
        int ix = (int)fx, iy = (int)fy;
        int inb = (ix >= 0 && ix < WW && iy >= 0 && iy < HH) ? 1 : 0;
        int ixc = min(max(ix, 0), WW - 1);
        int iyc = min(max(iy, 0), HH - 1);
        float m = (float)inb;
        const float* img = ref + b * 3 * HW + iyc * WW + ixc;
        float p0 = __fmul_rn(img[0], m);
        float p1 = __fmul_rn(img[HW], m);
        float p2 = __fmul_rn(img[2 * HW], m);
        float psq = __fadd_rn(__fadd_rn(__fmul_rn(p0, p0), __fmul_rn(p1, p1)),
                              __fmul_rn(p2, p2));
        spool[tid] = make_float4(p0, p1, p2, psq);
    }
    __syncthreads();

    const float4* p0g = (const float4*)(ref + (size_t)b * 3 * HW);
    int myq = tid & 7;
    float4 sp = spool[myq];           // broadcast read

    // ---- phase 1: per-thread max-d over 8 coalesced sites ----
    float md = -3.4e38f;
    {
        int site = tid;
        float4 n0 = p0g[site], n1 = p0g[site + SITES], n2 = p0g[site + 2 * SITES];
        #pragma unroll 1
        for (int it = 0; it < 8; ++it) {
            float4 a0 = n0, a1 = n1, a2 = n2;
            int sn = (it < 7) ? (site + 1024) : site;
            n0 = p0g[sn]; n1 = p0g[sn + SITES]; n2 = p0g[sn + 2 * SITES];
            #define SAMPM(comp)                                                         \
            {                                                                           \
                float nr = -0.5f * fmaf(a2.comp, a2.comp, fmaf(a1.comp, a1.comp,        \
                                  a0.comp * a0.comp));                                  \
                float d  = fmaf(a2.comp, sp.z, fmaf(a1.comp, sp.y,                      \
                               fmaf(a0.comp, sp.x, nr)));                               \
                md = fmaxf(md, d);                                                      \
            }
            SAMPM(x) SAMPM(y) SAMPM(z) SAMPM(w)
            #undef SAMPM
            site = sn;
        }
    }
    seg[tid] = fkey(-md);             // query myq's sample j=tid>>3 at flat [tid]

    // early-issue phase-3 first loads (in flight across phase 2)
    int site3 = tid;
    float4 f0 = p0g[site3], f1 = p0g[site3 + SITES], f2 = p0g[site3 + 2 * SITES];

    __syncthreads();

    // ---- phase 2: per-query threshold (wave w -> query w) ----
    if (wid < 8) {
        uint32_t v0 = seg[lane * 8 + wid];          // one-time strided reads
        uint32_t v1 = seg[(lane + 64) * 8 + wid];
        uint32_t lo = 0x00800000u, hi = 0xFF7FFFFFu;
        #pragma unroll 1
        for (int t = 0; t < 24; ++t) {
            uint32_t mid = lo + ((hi - lo) >> 1);
            int c = ((v0 <= mid) ? 1 : 0) + ((v1 <= mid) ? 1 : 0);
            #pragma unroll
            for (int off = 32; off >= 1; off >>= 1) c += __shfl_xor(c, off, 64);
            if (c >= KK) hi = mid; else lo = mid + 1;
        }
        float hval = -inv_fkey(hi) - PAD_FILT;
        if (qg == 31 && wid == 7) hval = 3.0e38f;   // l==255: never pass
        if (lane == 0) sh[wid] = hval;
    }
    __syncthreads();

    // ---- phase 3: full-image scan, segment push, no atomics ----
    float px[8], py[8], pz[8], hq[8];
    #pragma unroll
    for (int q = 0; q < 8; ++q) {
        float4 s = spool[q];
        px[q] = s.x; py[q] = s.y; pz[q] = s.z; hq[q] = sh[q];
    }
    uint32_t scq0 = 0, scq1 = 0, scq2 = 0, scq3 = 0,
             scq4 = 0, scq5 = 0, scq6 = 0, scq7 = 0;

    #pragma unroll 1
    for (int it = 0; it < 9; ++it) {           // 9*1024 = 9216 sites
        float4 a0 = f0, a1 = f1, a2 = f2;
        int sn = (it < 8) ? (site3 + 1024) : site3;
        f0 = p0g[sn]; f1 = p0g[sn + SITES]; f2 = p0g[sn + 2 * SITES];
        int base = site3 * 4;

        float nrx = -0.5f * fmaf(a2.x, a2.x, fmaf(a1.x, a1.x, a0.x * a0.x));
        float nry = -0.5f * fmaf(a2.y, a2.y, fmaf(a1.y, a1.y, a0.y * a0.y));
        float nrz = -0.5f * fmaf(a2.z, a2.z, fmaf(a1.z, a1.z, a0.z * a0.z));
        float nrw = -0.5f * fmaf(a2.w, a2.w, fmaf(a1.w, a1.w, a0.w * a0.w));

        #define QPUSH(q, scq)                                                           \
        {                                                                               \
            float d0 = fmaf(a2.x, pz[q], fmaf(a1.x, py[q], fmaf(a0.x, px[q], nrx)));    \
            float d1 = fmaf(a2.y, pz[q], fmaf(a1.y, py[q], fmaf(a0.y, px[q], nry)));    \
            float d2 = fmaf(a2.z, pz[q], fmaf(a1.z, py[q], fmaf(a0.z, px[q], nrz)));    \
            float d3 = fmaf(a2.w, pz[q], fmaf(a1.w, py[q], fmaf(a0.w, px[q], nrw)));    \
            u64 m0 = __ballot(d0 >= hq[q]);                                             \
            u64 m1 = __ballot(d1 >= hq[q]);                                             \
            u64 m2 = __ballot(d2 >= hq[q]);                                             \
            u64 m3 = __ballot(d3 >= hq[q]);                                             \
            if (m0 | m1 | m2 | m3) {          /* wave-uniform scalar branch */          \
                uint32_t sb = ((q) * NW + wid) * SEGSZ;                                 \
                uint32_t c = scq;                                                       \
                if (d0 >= hq[q]) { uint32_t s = c + mbcnt64(m0);                        \
                                   if (s < SEGSZ) seg[sb + s] = (uint32_t)(base + 0); } \
                c += (uint32_t)__popcll(m0);                                            \
                if (d1 >= hq[q]) { uint32_t s = c + mbcnt64(m1);                        \
                                   if (s < SEGSZ) seg[sb + s] = (uint32_t)(base + 1); } \
                c += (uint32_t)__popcll(m1);                                            \
                if (d2 >= hq[q]) { uint32_t s = c + mbcnt64(m2);                        \
                                   if (s < SEGSZ) seg[sb + s] = (uint32_t)(base + 2); } \
                c += (uint32_t)__popcll(m2);                                            \
                if (d3 >= hq[q]) { uint32_t s = c + mbcnt64(m3);                        \
                                   if (s < SEGSZ) seg[sb + s] = (uint32_t)(base + 3); } \
                c += (uint32_t)__popcll(m3);                                            \
                scq = c;                                                                \
            }                                                                           \
        }
        QPUSH(0, scq0) QPUSH(1, scq1) QPUSH(2, scq2) QPUSH(3, scq3)
        QPUSH(4, scq4) QPUSH(5, scq5) QPUSH(6, scq6) QPUSH(7, scq7)
        #undef QPUSH
        site3 = sn;
    }
    if (lane == 0) {
        scnts[0 * NW + wid] = scq0; scnts[1 * NW + wid] = scq1;
        scnts[2 * NW + wid] = scq2; scnts[3 * NW + wid] = scq3;
        scnts[4 * NW + wid] = scq4; scnts[5 * NW + wid] = scq5;
        scnts[6 * NW + wid] = scq6; scnts[7 * NW + wid] = scq7;
    }
    __syncthreads();

    // ---- phase 4: compact + exact selection + loss (wave w -> query w) ----
    if (wid < 8) {
        int l  = qg * 8 + wid;
        int bl = b * 256 + l;
        if (l == 255) {                    // its top-16 feeds only excluded row 0
            if (lane == 0) partial[bl] = 0.0f;
        } else {
            // read the 16 segment counts (broadcast), compact into [wid*UCAP ..)
            uint32_t cA[16];
            #pragma unroll
            for (int j = 0; j < 16; ++j) cA[j] = scnts[wid * NW + j];
            bool ovf = false;
            uint32_t pref = 0;
            #pragma unroll
            for (int j = 0; j < 16; ++j) {
                uint32_t c = cA[j];
                ovf = ovf || (c > SEGSZ);
                uint32_t cc = min(c, (uint32_t)SEGSZ);
                if (lane < cc && pref + lane < UCAP)
                    compactb[wid * UCAP + pref + lane] =
                        seg[(wid * NW + j) * SEGSZ + lane];
                pref += cc;
            }
            uint32_t U = pref;
            if (U > UCAP) ovf = true;

            float px1 = pred[(size_t)(bl + 1) * 8 + 0];
            float py1 = pred[(size_t)(bl + 1) * 8 + 1];
            float4 pqv = spool[wid];
            const float* rb = ref + (size_t)b * 3 * HW;
            float dmin = 3.4e38f, btx = 0.0f, bty = 0.0f;

            if (!ovf) {
                u64 r0, r1, r2, r3, r4, r5, r6, r7;
                #define LOADJ(jj, rj)                                                   \
                {                                                                       \
                    uint32_t e = (jj) * 64 + lane;                                      \
                    u64 v = ~0ull;                                                      \
                    if (e < U) {                                                        \
                        uint32_t pidx = compactb[wid * UCAP + e];                       \
                        float c0v = rb[pidx], c1v = rb[pidx + HW], c2v = rb[pidx + 2 * HW]; \
                        float rs = exact_rsq(c0v, c1v, c2v);                            \
                        float sx = exact_sim(c0v, c1v, c2v, rs, pqv);                   \
                        v = ((u64)fkey(sx) << 32) | pidx;                               \
                    }                                                                   \
                    rj = v;                                                             \
                }
                LOADJ(0, r0) LOADJ(1, r1) LOADJ(2, r2) LOADJ(3, r3)
                LOADJ(4, r4) LOADJ(5, r5) LOADJ(6, r6) LOADJ(7, r7)
                #undef LOADJ

                #pragma unroll 1
                for (int rnd = 0; rnd < 16; ++rnd) {
                    u64 mloc = umin64(umin64(umin64(r0, r1), umin64(r2, r3)),
                                      umin64(umin64(r4, r5), umin64(r6, r7)));
                    u64 gm = wave_min_u64(mloc);
                    if (gm != ~0ull) LOSS_STEP(gm)
                    r0 = (r0 == gm) ? ~0ull : r0;
                    r1 = (r1 == gm) ? ~0ull : r1;
                    r2 = (r2 == gm) ? ~0ull : r2;
                    r3 = (r3 == gm) ? ~0ull : r3;
                    r4 = (r4 == gm) ? ~0ull : r4;
                    r5 = (r5 == gm) ? ~0ull : r5;
                    r6 = (r6 == gm) ? ~0ull : r6;
                    r7 = (r7 == gm) ? ~0ull : r7;
                }
            } else {
                // safety net (P ~ 1e-20): exact full rescan for this query
                u64 kept16[KK];
                #pragma unroll
                for (int j = 0; j < KK; ++j) kept16[j] = ~0ull;
                const float4* pg = (const float4*)rb;
                #pragma unroll 1
                for (int st = lane; st < SITES; st += 64) {
                    float4 a0 = pg[st], a1 = pg[st + SITES], a2 = pg[st + 2 * SITES];
                    int base = st * 4;
                    #define FB(comp, ei)                                                \
                    {                                                                   \
                        float rs = exact_rsq(a0.comp, a1.comp, a2.comp);                \
                        float sx = exact_sim(a0.comp, a1.comp, a2.comp, rs, pqv);       \
                        u64 key = ((u64)fkey(sx) << 32) | (uint32_t)(base + (ei));      \
                        if (key < kept16[KK - 1]) insert64(kept16, key);                \
                    }
                    FB(x, 0) FB(y, 1) FB(z, 2) FB(w, 3)
                    #undef FB
                }
                #pragma unroll 1
                for (int rnd = 0; rnd < 16; ++rnd) {
                    u64 gm = wave_min_u64(kept16[0]);
                    if (kept16[0] == gm) {        // exactly one lane (unique keys)
                        #pragma unroll
                        for (int j = 0; j < KK - 1; ++j) kept16[j] = kept16[j + 1];
                        kept16[KK - 1] = ~0ull;
                    }
                    LOSS_STEP(gm)
                }
            }

            if (lane == 0) {
                float ex = __fsub_rn(px1, btx);
                float ey = __fsub_rn(py1, bty);
                partial[bl] = __fadd_rn(__fmul_rn(ex, ex), __fmul_rn(ey, ey));
            }
        }
    }
}

// ---------- reduce 2048 partials -> mean ----------
__global__ __launch_bounds__(256) void reduce_kernel(const float* __restrict__ partial,
                                                     float* __restrict__ out) {
    __shared__ double sred[256];
    double a = 0.0;
    #pragma unroll
    for (int i = 0; i < 8; ++i) a += (double)partial[i * 256 + threadIdx.x];
    sred[threadIdx.x] = a;
    __syncthreads();
    for (int s = 128; s > 0; s >>= 1) {
        if (threadIdx.x < s) sred[threadIdx.x] += sred[threadIdx.x + s];
        __syncthreads();
    }
    if (threadIdx.x == 0) out[0] = (float)(sred[0] / 2040.0);
}

// ---------- launch ----------
extern "C" void kernel_launch(void* const* d_in, const int* in_sizes, int n_in,
                              void* d_out, int out_size, void* d_ws, size_t ws_size,
                              hipStream_t stream) {
    const float* pred = (const float*)d_in[0];   // (8,256,8) f32
    const float* ref  = (const float*)d_in[1];   // (8,3,192,192) f32
    float* out = (float*)d_out;

    float* partial = (float*)d_ws;               // 2048 floats, fully overwritten

    fused_kernel <<<256, 1024, 0, stream>>>(pred, ref, partial);
    reduce_kernel<<<  1,  256, 0, stream>>>(partial, out);
}

// Round 5
// 90.507 us; speedup vs baseline: 1.6023x; 1.1075x over previous
//
#include <hip/hip_runtime.h>
#include <stdint.h>

#define BS 8
#define HH 192
#define WW 192
#define HW (HH*WW)          /* 36864 pixels per plane */
#define KK 16
#define SITES 9216          /* float4 sites per plane */
#define NQ 4                /* queries per block */
#define NW 16               /* waves per block */
#define SEGSZ 32            /* per-(query,wave) segment capacity; E ~ 2.5 */
#define UCAP 256            /* per-query merged candidate cap (4 regs/lane) */
#define PAD_FILT 4e-5f      /* filter safety: fma-vs-exact error ~1e-6 */

typedef unsigned long long u64;

// ---------- helpers ----------

__device__ __forceinline__ uint32_t fkey(float f) {
    uint32_t u = __float_as_uint(f);
    uint32_t mask = (uint32_t)((int32_t)u >> 31) | 0x80000000u;
    return u ^ mask;
}
__device__ __forceinline__ float inv_fkey(uint32_t v) {
    uint32_t u = (v & 0x80000000u) ? (v ^ 0x80000000u) : ~v;
    return __uint_as_float(u);
}

__device__ __forceinline__ u64 umin64(u64 a, u64 b) { return a < b ? a : b; }

__device__ __forceinline__ uint32_t mbcnt64(u64 m) {
    return __builtin_amdgcn_mbcnt_hi((uint32_t)(m >> 32),
            __builtin_amdgcn_mbcnt_lo((uint32_t)m, 0));
}

__device__ __forceinline__ u64 wave_min_u64(u64 v) {   // fallback path only
    #pragma unroll
    for (int off = 32; off >= 1; off >>= 1) {
        uint32_t lo = (uint32_t)v, hi = (uint32_t)(v >> 32);
        lo = __shfl_xor(lo, off, 64);
        hi = __shfl_xor(hi, off, 64);
        u64 o = ((u64)hi << 32) | lo;
        v = umin64(v, o);
    }
    return v;
}

// sorted ascending insertion, 16 deep (fallback path only)
__device__ __forceinline__ void insert64(u64 (&kept)[KK], u64 key) {
    #pragma unroll
    for (int j = KK - 1; j >= 1; --j) {
        u64 a = kept[j - 1];
        u64 mn = umin64(kept[j], key);
        kept[j] = (key < a) ? a : mn;
    }
    kept[0] = umin64(kept[0], key);
}

// exact (reference-rounded) similarity pieces — bit-identical to validated kernel
__device__ __forceinline__ float exact_rsq(float a, float b, float c) {
    return __fadd_rn(__fadd_rn(__fmul_rn(a, a), __fmul_rn(b, b)), __fmul_rn(c, c));
}
__device__ __forceinline__ float exact_sim(float c0, float c1, float c2, float rsq, float4 pq) {
    float cr = __fadd_rn(__fadd_rn(__fmul_rn(c0, pq.x), __fmul_rn(c1, pq.y)), __fmul_rn(c2, pq.z));
    return __fadd_rn(__fsub_rn(rsq, __fmul_rn(2.0f, cr)), pq.w);
}

// loss-term tracking (fallback path): strict < keeps first (lowest-rank) min
#define LOSS_STEP(gmv)                                                   \
{                                                                        \
    uint32_t idxv = (uint32_t)(gmv);                                     \
    float tx = (float)(idxv % WW) / 192.0f;                              \
    float ty = (float)(idxv / WW) / 192.0f;                              \
    float ddx = __fsub_rn(px1, tx);                                      \
    float ddy = __fsub_rn(py1, ty);                                      \
    float dd = __fadd_rn(__fmul_rn(ddx, ddx), __fmul_rn(ddy, ddy));      \
    if (dd < dmin) { dmin = dd; btx = tx; bty = ty; }                    \
}

// ---------- fused kernel: block = (image, 4 queries), 1024 threads ----------
// P0: pooled/psq per query (exact, verbatim reference rounding)
// P1: sample sites 0..4095 ONCE, shared across all 4 queries; per-thread
//     per-query MAX d over its 16 px (sound: 16th-largest of 1024 disjoint
//     group-maxima <= sample 16th-best <= image 16th-best)
// P2: waves 0..3 — exact 16th-smallest via 32-step ballot-count binsearch
//     (no cross-lane shuffles); h = bound - PAD_FILT
// P3: all 16 waves scan the full image once; shared -0.5*rsq; passing pixel
//     indices -> private per-(query,wave) LDS segments via ballot+mbcnt
// P4: waves 0..3 — compact, exact sims; EXACT top-16 by two-stage ballot
//     binsearch on (simkey, pidx); argmin via lexicographic (dd,key) min
//     (== reference's rank-ordered argmin with first-min tie-break)
__global__ __launch_bounds__(1024, 8) void fused_kernel(const float* __restrict__ pred,
                                                        const float* __restrict__ ref,
                                                        float* __restrict__ partial) {
    __shared__ uint32_t mxseg[4096];          // 16 KB: P1 maxima, then P3 segments
    __shared__ uint32_t compactb[NQ * UCAP];  // 4 KB
    __shared__ uint32_t scnts[NQ * NW];
    __shared__ float4 spool[NQ];
    __shared__ float shq[NQ];

    int tid  = threadIdx.x;
    int lane = tid & 63;
    int wid  = tid >> 6;              // 0..15
    int b  = blockIdx.x & 7;          // XCD swizzle: image b -> XCD b
    int qg = blockIdx.x >> 3;         // 0..63

    // ---- P0 ----
    if (tid < NQ) {
        int l = qg * NQ + tid;
        int i = l * BS + b;           // scrambled flat grid row
        int b2 = i >> 8, l2 = i & 255;
        const float* pr = pred + ((b2 * 256 + l2) * 8);
        float x = pr[0], y = pr[1];
        float fx = rintf(__fsub_rn(__fmul_rn(x, 192.0f), 0.5f));
        float fy = rintf(__fsub_rn(__fmul_rn(y, 192.0f), 0.5f));
        int ix = (int)fx, iy = (int)fy;
        int inb = (ix >= 0 && ix < WW && iy >= 0 && iy < HH) ? 1 : 0;
        int ixc = min(max(ix, 0), WW - 1);
        int iyc = min(max(iy, 0), HH - 1);
        float m = (float)inb;
        const float* img = ref + b * 3 * HW + iyc * WW + ixc;
        float p0 = __fmul_rn(img[0], m);
        float p1 = __fmul_rn(img[HW], m);
        float p2 = __fmul_rn(img[2 * HW], m);
        float psq = __fadd_rn(__fadd_rn(__fmul_rn(p0, p0), __fmul_rn(p1, p1)),
                              __fmul_rn(p2, p2));
        spool[tid] = make_float4(p0, p1, p2, psq);
    }
    __syncthreads();

    const float4* p0g = (const float4*)(ref + (size_t)b * 3 * HW);
    float qx[NQ], qy[NQ], qz[NQ];
    #pragma unroll
    for (int q = 0; q < NQ; ++q) {
        float4 s = spool[q];
        qx[q] = s.x; qy[q] = s.y; qz[q] = s.z;
    }

    // ---- P1: shared sampling, per-thread per-query max ----
    float md0 = -3.4e38f, md1 = -3.4e38f, md2 = -3.4e38f, md3 = -3.4e38f;
    #pragma unroll 1
    for (int it = 0; it < 4; ++it) {
        int site = tid + it * 1024;
        float4 a0 = p0g[site], a1 = p0g[site + SITES], a2 = p0g[site + 2 * SITES];
        #define SAMP(comp)                                                              \
        {                                                                               \
            float nr = -0.5f * fmaf(a2.comp, a2.comp, fmaf(a1.comp, a1.comp,            \
                              a0.comp * a0.comp));                                      \
            float d0_ = fmaf(a2.comp, qz[0], fmaf(a1.comp, qy[0], fmaf(a0.comp, qx[0], nr))); \
            float d1_ = fmaf(a2.comp, qz[1], fmaf(a1.comp, qy[1], fmaf(a0.comp, qx[1], nr))); \
            float d2_ = fmaf(a2.comp, qz[2], fmaf(a1.comp, qy[2], fmaf(a0.comp, qx[2], nr))); \
            float d3_ = fmaf(a2.comp, qz[3], fmaf(a1.comp, qy[3], fmaf(a0.comp, qx[3], nr))); \
            md0 = fmaxf(md0, d0_); md1 = fmaxf(md1, d1_);                               \
            md2 = fmaxf(md2, d2_); md3 = fmaxf(md3, d3_);                               \
        }
        SAMP(x) SAMP(y) SAMP(z) SAMP(w)
        #undef SAMP
    }
    mxseg[0 * 1024 + tid] = fkey(-md0);
    mxseg[1 * 1024 + tid] = fkey(-md1);
    mxseg[2 * 1024 + tid] = fkey(-md2);
    mxseg[3 * 1024 + tid] = fkey(-md3);
    __syncthreads();

    // ---- P2: exact 16th-smallest of 1024 keys, ballot-count binsearch ----
    if (wid < NQ) {
        uint32_t v[16];
        #pragma unroll
        for (int j = 0; j < 16; ++j) v[j] = mxseg[wid * 1024 + lane + 64 * j];
        uint32_t lo = 0u, hi = 0xFFFFFFFFu;
        #pragma unroll 1
        for (int t = 0; t < 32; ++t) {
            uint32_t mid = lo + ((hi - lo) >> 1);
            int c = 0;
            #pragma unroll
            for (int j = 0; j < 16; ++j) c += (int)__popcll(__ballot(v[j] <= mid));
            if (c >= KK) hi = mid; else lo = mid + 1;
        }
        float hval = -inv_fkey(hi) - PAD_FILT;
        if (qg == 63 && wid == 3) hval = 3.0e38f;   // l==255: never pass
        if (lane == 0) shq[wid] = hval;
    }
    __syncthreads();

    // ---- P3: full-image scan, segment push (no atomics, no shuffles) ----
    float hq0 = shq[0], hq1 = shq[1], hq2 = shq[2], hq3 = shq[3];
    uint32_t scq0 = 0, scq1 = 0, scq2 = 0, scq3 = 0;

    #pragma unroll 1
    for (int it = 0; it < 9; ++it) {           // 9*1024 = 9216 sites
        int site = tid + it * 1024;
        float4 a0 = p0g[site], a1 = p0g[site + SITES], a2 = p0g[site + 2 * SITES];
        int base = site * 4;

        float nrx = -0.5f * fmaf(a2.x, a2.x, fmaf(a1.x, a1.x, a0.x * a0.x));
        float nry = -0.5f * fmaf(a2.y, a2.y, fmaf(a1.y, a1.y, a0.y * a0.y));
        float nrz = -0.5f * fmaf(a2.z, a2.z, fmaf(a1.z, a1.z, a0.z * a0.z));
        float nrw = -0.5f * fmaf(a2.w, a2.w, fmaf(a1.w, a1.w, a0.w * a0.w));

        #define QPUSH(qi, hqv, scq)                                                     \
        {                                                                               \
            float d0 = fmaf(a2.x, qz[qi], fmaf(a1.x, qy[qi], fmaf(a0.x, qx[qi], nrx))); \
            float d1 = fmaf(a2.y, qz[qi], fmaf(a1.y, qy[qi], fmaf(a0.y, qx[qi], nry))); \
            float d2 = fmaf(a2.z, qz[qi], fmaf(a1.z, qy[qi], fmaf(a0.z, qx[qi], nrz))); \
            float d3 = fmaf(a2.w, qz[qi], fmaf(a1.w, qy[qi], fmaf(a0.w, qx[qi], nrw))); \
            u64 m0 = __ballot(d0 >= hqv);                                               \
            u64 m1 = __ballot(d1 >= hqv);                                               \
            u64 m2 = __ballot(d2 >= hqv);                                               \
            u64 m3 = __ballot(d3 >= hqv);                                               \
            if (m0 | m1 | m2 | m3) {          /* wave-uniform scalar branch */          \
                uint32_t sb = ((qi) * NW + wid) * SEGSZ;                                \
                uint32_t c = scq;                                                       \
                if (d0 >= hqv) { uint32_t s = c + mbcnt64(m0);                          \
                                 if (s < SEGSZ) mxseg[sb + s] = (uint32_t)(base + 0); } \
                c += (uint32_t)__popcll(m0);                                            \
                if (d1 >= hqv) { uint32_t s = c + mbcnt64(m1);                          \
                                 if (s < SEGSZ) mxseg[sb + s] = (uint32_t)(base + 1); } \
                c += (uint32_t)__popcll(m1);                                            \
                if (d2 >= hqv) { uint32_t s = c + mbcnt64(m2);                          \
                                 if (s < SEGSZ) mxseg[sb + s] = (uint32_t)(base + 2); } \
                c += (uint32_t)__popcll(m2);                                            \
                if (d3 >= hqv) { uint32_t s = c + mbcnt64(m3);                          \
                                 if (s < SEGSZ) mxseg[sb + s] = (uint32_t)(base + 3); } \
                c += (uint32_t)__popcll(m3);                                            \
                scq = c;                                                                \
            }                                                                           \
        }
        QPUSH(0, hq0, scq0) QPUSH(1, hq1, scq1) QPUSH(2, hq2, scq2) QPUSH(3, hq3, scq3)
        #undef QPUSH
    }
    if (lane == 0) {
        scnts[0 * NW + wid] = scq0; scnts[1 * NW + wid] = scq1;
        scnts[2 * NW + wid] = scq2; scnts[3 * NW + wid] = scq3;
    }
    __syncthreads();

    // ---- P4: compact + exact top-16 + loss (wave w -> query w) ----
    if (wid < NQ) {
        int l  = qg * NQ + wid;
        int bl = b * 256 + l;
        if (l == 255) {                    // its top-16 feeds only excluded row 0
            if (lane == 0) partial[bl] = 0.0f;
        } else {
            bool ovf = false;
            uint32_t pref = 0;
            #pragma unroll
            for (int j = 0; j < NW; ++j) {
                uint32_t c = scnts[wid * NW + j];
                ovf = ovf || (c > SEGSZ);
                uint32_t cc = min(c, (uint32_t)SEGSZ);
                if (lane < cc && pref + lane < UCAP)
                    compactb[wid * UCAP + pref + lane] =
                        mxseg[(wid * NW + j) * SEGSZ + lane];
                pref += cc;
            }
            uint32_t U = pref;
            if (U > UCAP) ovf = true;

            float px1 = pred[(size_t)(bl + 1) * 8 + 0];
            float py1 = pred[(size_t)(bl + 1) * 8 + 1];
            float4 pqv = spool[wid];
            const float* rb = ref + (size_t)b * 3 * HW;

            if (!ovf) {
                // candidate keys (simkey hi, pidx lo), exact sims
                uint32_t kh0, kh1, kh2, kh3, kl0, kl1, kl2, kl3;
                #define LOADJ(jj, kh, kl)                                               \
                {                                                                       \
                    uint32_t e = (jj) * 64 + lane;                                      \
                    uint32_t h_ = 0xFFFFFFFFu, l_ = 0xFFFFFFFFu;                        \
                    if (e < U) {                                                        \
                        uint32_t pidx = compactb[wid * UCAP + e];                       \
                        float c0v = rb[pidx], c1v = rb[pidx + HW], c2v = rb[pidx + 2 * HW]; \
                        float rs = exact_rsq(c0v, c1v, c2v);                            \
                        float sx = exact_sim(c0v, c1v, c2v, rs, pqv);                   \
                        h_ = fkey(sx); l_ = pidx;                                       \
                    }                                                                   \
                    kh = h_; kl = l_;                                                   \
                }
                LOADJ(0, kh0, kl0) LOADJ(1, kh1, kl1) LOADJ(2, kh2, kl2) LOADJ(3, kh3, kl3)
                #undef LOADJ

                // stage A: smallest H with #{khi <= H} >= 16 (exact; padding
                // khi=0xFFFFFFFF can't distort since real khi < 0xFF800000)
                uint32_t lo = 0u, hi = 0xFFFFFFFFu;
                #pragma unroll 1
                for (int t = 0; t < 32; ++t) {
                    uint32_t mid = lo + ((hi - lo) >> 1);
                    int c = (int)__popcll(__ballot(kh0 <= mid))
                          + (int)__popcll(__ballot(kh1 <= mid))
                          + (int)__popcll(__ballot(kh2 <= mid))
                          + (int)__popcll(__ballot(kh3 <= mid));
                    if (c >= KK) hi = mid; else lo = mid + 1;
                }
                uint32_t Hh = hi;
                int c1 = (int)__popcll(__ballot(kh0 < Hh))
                       + (int)__popcll(__ballot(kh1 < Hh))
                       + (int)__popcll(__ballot(kh2 < Hh))
                       + (int)__popcll(__ballot(kh3 < Hh));
                int need = KK - c1;                    // >= 1 by minimality of Hh
                u64 e0 = __ballot(kh0 == Hh), e1 = __ballot(kh1 == Hh);
                u64 e2 = __ballot(kh2 == Hh), e3 = __ballot(kh3 == Hh);
                // stage B: smallest L with #{khi==Hh && klo<=L} >= need
                // (pidx unique => count lands exactly on need => |sel| == 16)
                lo = 0u; hi = 0xFFFFFFFFu;
                #pragma unroll 1
                for (int t = 0; t < 32; ++t) {
                    uint32_t mid = lo + ((hi - lo) >> 1);
                    int c = (int)__popcll(e0 & __ballot(kl0 <= mid))
                          + (int)__popcll(e1 & __ballot(kl1 <= mid))
                          + (int)__popcll(e2 & __ballot(kl2 <= mid))
                          + (int)__popcll(e3 & __ballot(kl3 <= mid));
                    if (c >= need) hi = mid; else lo = mid + 1;
                }
                uint32_t Lh = hi;

                // local lexicographic min of (ddbits, khi, klo) over selected
                // == argmin over rank-ordered targets with first-min tie-break
                uint32_t bd = 0xFFFFFFFFu, bh = 0xFFFFFFFFu, bo = 0xFFFFFFFFu;
                #define SELJ(kh, kl)                                                    \
                {                                                                       \
                    bool sel = (kh < Hh) || (kh == Hh && kl <= Lh);                     \
                    if (sel) {                                                          \
                        uint32_t idxv = kl;                                             \
                        float tx = (float)(idxv % WW) / 192.0f;                         \
                        float ty = (float)(idxv / WW) / 192.0f;                         \
                        float ddx = __fsub_rn(px1, tx);                                 \
                        float ddy = __fsub_rn(py1, ty);                                 \
                        float dd = __fadd_rn(__fmul_rn(ddx, ddx), __fmul_rn(ddy, ddy)); \
                        uint32_t db = __float_as_uint(dd);   /* dd>=0: monotone */      \
                        bool lt = (db < bd) ||                                          \
                                  (db == bd && (kh < bh || (kh == bh && kl < bo)));     \
                        if (lt) { bd = db; bh = kh; bo = kl; }                          \
                    }                                                                   \
                }
                SELJ(kh0, kl0) SELJ(kh1, kl1) SELJ(kh2, kl2) SELJ(kh3, kl3)
                #undef SELJ
                #pragma unroll
                for (int off = 32; off >= 1; off >>= 1) {
                    uint32_t od = __shfl_xor(bd, off, 64);
                    uint32_t oh = __shfl_xor(bh, off, 64);
                    uint32_t oo = __shfl_xor(bo, off, 64);
                    bool lt = (od < bd) ||
                              (od == bd && (oh < bh || (oh == bh && oo < bo)));
                    if (lt) { bd = od; bh = oh; bo = oo; }
                }
                if (lane == 0) {
                    uint32_t idxv = bo;
                    float tx = (float)(idxv % WW) / 192.0f;
                    float ty = (float)(idxv / WW) / 192.0f;
                    float ex = __fsub_rn(px1, tx);
                    float ey = __fsub_rn(py1, ty);
                    partial[bl] = __fadd_rn(__fmul_rn(ex, ex), __fmul_rn(ey, ey));
                }
            } else {
                // safety net (P ~ 1e-20): exact full rescan for this query
                float dmin = 3.4e38f, btx = 0.0f, bty = 0.0f;
                u64 kept16[KK];
                #pragma unroll
                for (int j = 0; j < KK; ++j) kept16[j] = ~0ull;
                const float4* pg = (const float4*)rb;
                #pragma unroll 1
                for (int st = lane; st < SITES; st += 64) {
                    float4 a0 = pg[st], a1 = pg[st + SITES], a2 = pg[st + 2 * SITES];
                    int base = st * 4;
                    #define FB(comp, ei)                                                \
                    {                                                                   \
                        float rs = exact_rsq(a0.comp, a1.comp, a2.comp);                \
                        float sx = exact_sim(a0.comp, a1.comp, a2.comp, rs, pqv);       \
                        u64 key = ((u64)fkey(sx) << 32) | (uint32_t)(base + (ei));      \
                        if (key < kept16[KK - 1]) insert64(kept16, key);                \
                    }
                    FB(x, 0) FB(y, 1) FB(z, 2) FB(w, 3)
                    #undef FB
                }
                #pragma unroll 1
                for (int rnd = 0; rnd < 16; ++rnd) {
                    u64 gm = wave_min_u64(kept16[0]);
                    if (kept16[0] == gm) {        // exactly one lane (unique keys)
                        #pragma unroll
                        for (int j = 0; j < KK - 1; ++j) kept16[j] = kept16[j + 1];
                        kept16[KK - 1] = ~0ull;
                    }
                    LOSS_STEP(gm)
                }
                if (lane == 0) {
                    float ex = __fsub_rn(px1, btx);
                    float ey = __fsub_rn(py1, bty);
                    partial[bl] = __fadd_rn(__fmul_rn(ex, ex), __fmul_rn(ey, ey));
                }
            }
        }
    }
}

// ---------- reduce 2048 partials -> mean ----------
__global__ __launch_bounds__(256) void reduce_kernel(const float* __restrict__ partial,
                                                     float* __restrict__ out) {
    __shared__ double sred[256];
    double a = 0.0;
    #pragma unroll
    for (int i = 0; i < 8; ++i) a += (double)partial[i * 256 + threadIdx.x];
    sred[threadIdx.x] = a;
    __syncthreads();
    for (int s = 128; s > 0; s >>= 1) {
        if (threadIdx.x < s) sred[threadIdx.x] += sred[threadIdx.x + s];
        __syncthreads();
    }
    if (threadIdx.x == 0) out[0] = (float)(sred[0] / 2040.0);
}

// ---------- launch ----------
extern "C" void kernel_launch(void* const* d_in, const int* in_sizes, int n_in,
                              void* d_out, int out_size, void* d_ws, size_t ws_size,
                              hipStream_t stream) {
    const float* pred = (const float*)d_in[0];   // (8,256,8) f32
    const float* ref  = (const float*)d_in[1];   // (8,3,192,192) f32
    float* out = (float*)d_out;

    float* partial = (float*)d_ws;               // 2048 floats, fully overwritten

    fused_kernel <<<512, 1024, 0, stream>>>(pred, ref, partial);
    reduce_kernel<<<  1,  256, 0, stream>>>(partial, out);
}